// Round 1
// baseline (175.665 us; speedup 1.0000x reference)
//
#include <hip/hip_runtime.h>

#define TPG   4096    // nodes per graph (T)
#define NHEAD 4
#define DIMD  128
#define NEG   0.2f

// ---------------------------------------------------------------- edge loads
__device__ __forceinline__ int load_edge(const void* ei, int is64, long idx) {
  if (is64) return (int)((const long long*)ei)[idx];
  return ((const int*)ei)[idx];
}

// Detect whether edge_index arrived as int64 (high dwords all zero) or int32.
__global__ void k_detect(const unsigned int* __restrict__ ei, int* __restrict__ flag) {
  int t = threadIdx.x;
  int nz = 0;
  for (int i = t; i < 4096; i += 64) nz |= (ei[2 * i + 1] != 0u);
  unsigned long long b = __ballot(nz);
  if (t == 0) *flag = (b == 0ull) ? 1 : 0;   // 1 => int64 layout
}

__global__ void k_zero(int* __restrict__ p, int n) {
  int i = blockIdx.x * blockDim.x + threadIdx.x;
  if (i < n) p[i] = 0;
}

// ------------------------------------------------- GEMM h = x*W^T + att dots
// block = 256 threads, 16 nodes/block. thread(n_sub = t&15, cgrp = t>>4)
// computes 8 channels c = cgrp*8 .. +7. Wave w owns head w exactly.
__global__ __launch_bounds__(256) void k_gemm(
    const float* __restrict__ x, const float* __restrict__ W,
    const float* __restrict__ atts, const float* __restrict__ attd,
    float* __restrict__ h, float* __restrict__ as_n, float* __restrict__ ad_n) {
  __shared__ float4 xs4[16][33];   // +1 float4 pad: banks 4*(n+d4)%32 -> 2-way max
  int t = threadIdx.x;
  int base = blockIdx.x * 16;
  const float4* x4 = (const float4*)x;
  for (int i = t; i < 512; i += 256) {
    xs4[i >> 5][i & 31] = x4[base * 32 + i];
  }
  __syncthreads();

  int n_sub = t & 15, cgrp = t >> 4;
  int c0 = cgrp * 8;
  const float4* W4 = (const float4*)W;
  float acc[8];
#pragma unroll
  for (int k = 0; k < 8; ++k) acc[k] = 0.f;

  for (int db = 0; db < 32; db += 8) {     // 32 d per chunk
    float4 xa[8];
#pragma unroll
    for (int i = 0; i < 8; ++i) xa[i] = xs4[n_sub][db + i];
#pragma unroll
    for (int k = 0; k < 8; ++k) {
      const float4* wr = W4 + (c0 + k) * 32 + db;
      float a = acc[k];
#pragma unroll
      for (int i = 0; i < 8; ++i) {
        float4 w = wr[i];
        a = fmaf(xa[i].x, w.x, a);
        a = fmaf(xa[i].y, w.y, a);
        a = fmaf(xa[i].z, w.z, a);
        a = fmaf(xa[i].w, w.w, a);
      }
      acc[k] = a;
    }
  }

  int n = base + n_sub;
  float4* hp = (float4*)(h + (n << 7) + c0);
  hp[0] = make_float4(acc[0], acc[1], acc[2], acc[3]);
  hp[1] = make_float4(acc[4], acc[5], acc[6], acc[7]);

  // attention dots: head = cgrp>>2 = wave id; reduce over 4 cgrps via xor 16,32
  float ps = 0.f, pd = 0.f;
#pragma unroll
  for (int k = 0; k < 8; ++k) {
    ps = fmaf(acc[k], atts[c0 + k], ps);
    pd = fmaf(acc[k], attd[c0 + k], pd);
  }
  ps += __shfl_xor(ps, 16); ps += __shfl_xor(ps, 32);
  pd += __shfl_xor(pd, 16); pd += __shfl_xor(pd, 32);
  if ((t & 48) == 0) {                 // lanes 0..15 of each wave
    as_n[(n << 2) + (t >> 6)] = ps;
    ad_n[(n << 2) + (t >> 6)] = pd;
  }
}

// ------------------------------------------------------------------ CSR build
__global__ void k_hist(const void* __restrict__ ei, const int* __restrict__ flag,
                       int* __restrict__ counts, int E) {
  int e = blockIdx.x * blockDim.x + threadIdx.x;
  if (e >= E) return;
  int is64 = *flag;
  int dst = load_edge(ei, is64, (long)E + e);
  atomicAdd(&counts[dst], 1);
}

__global__ __launch_bounds__(1024) void k_scan(const int* __restrict__ counts,
                                               int* __restrict__ offs,
                                               int* __restrict__ cursor) {
  __shared__ int wsum[16];
  __shared__ int woff[17];
  int t = threadIdx.x;
  int b = t * 4;
  int v0 = counts[b], v1 = counts[b + 1], v2 = counts[b + 2], v3 = counts[b + 3];
  int s0 = v0 + v1 + v2 + v3;
  int lane = t & 63, w = t >> 6;
  int sc = s0;
#pragma unroll
  for (int off = 1; off < 64; off <<= 1) {
    int o = __shfl_up(sc, off);
    if (lane >= off) sc += o;
  }
  if (lane == 63) wsum[w] = sc;
  __syncthreads();
  if (t == 0) {
    int a = 0;
#pragma unroll
    for (int i = 0; i < 16; ++i) { woff[i] = a; a += wsum[i]; }
    woff[16] = a;
  }
  __syncthreads();
  int a = woff[w] + sc - s0;   // exclusive prefix of this thread's chunk
  offs[b] = a;     cursor[b] = a;     a += v0;
  offs[b + 1] = a; cursor[b + 1] = a; a += v1;
  offs[b + 2] = a; cursor[b + 2] = a; a += v2;
  offs[b + 3] = a; cursor[b + 3] = a;
  if (t == 1023) offs[4096] = woff[16];
}

__global__ void k_scatter(const void* __restrict__ ei, const int* __restrict__ flag,
                          int* __restrict__ cursor, int* __restrict__ esrc, int E) {
  int e = blockIdx.x * blockDim.x + threadIdx.x;
  if (e >= E) return;
  int is64 = *flag;
  int src = load_edge(ei, is64, e);
  int dst = load_edge(ei, is64, (long)E + e);
  int pos = atomicAdd(&cursor[dst], 1);
  esrc[pos] = src;
}

// -------------------------------------------- per-node softmax + aggregation
// one wave per node. Pass 1: (m,s) online softmax, 16 edge-groups x 4 heads.
// Pass 2: lane owns channels 2l,2l+1 (head = lane>>4); one coalesced 512B
// h-row gather per edge; no atomics.
__global__ __launch_bounds__(256) void k_aggr(
    const int* __restrict__ offs, const int* __restrict__ esrc,
    const float* __restrict__ h, const float* __restrict__ as_n,
    const float* __restrict__ ad_n, const float* __restrict__ bias,
    float* __restrict__ out) {
  int wid = (blockIdx.x << 2) + (threadIdx.x >> 6);
  int lane = threadIdx.x & 63;
  int n = wid;
  int tloc = n & (TPG - 1);
  int nodebase = n - tloc;
  int beg = offs[tloc], end = offs[tloc + 1];

  // ---- pass 1
  int hh = lane & 3;
  float adst = ad_n[(n << 2) + hh];
  float m = -1e30f, s = 0.f;
  if ((lane >> 2) == 0) {              // group 0 also takes the self-loop
    float e = as_n[(n << 2) + hh] + adst;
    e = e > 0.f ? e : NEG * e;
    m = e; s = 1.f;
  }
  for (int j = beg + (lane >> 2); j < end; j += 16) {
    int sg = nodebase + esrc[j];
    float e = as_n[(sg << 2) + hh] + adst;
    e = e > 0.f ? e : NEG * e;
    float mn = fmaxf(m, e);
    s = s * __expf(m - mn) + __expf(e - mn);
    m = mn;
  }
#pragma unroll
  for (int off = 4; off < 64; off <<= 1) {   // merge 16 groups, heads stay mod-4
    float m2 = __shfl_xor(m, off);
    float s2 = __shfl_xor(s, off);
    float mn = fmaxf(m, m2);
    s = s * __expf(m - mn) + s2 * __expf(m2 - mn);
    m = mn;
  }

  // ---- pass 2
  int myh = lane >> 4;
  float mH = __shfl(m, myh);           // lane myh holds stats of head myh
  float sH = __shfl(s, myh);
  float inv = 1.f / (sH + 1e-16f);
  float adst2 = ad_n[(n << 2) + myh];
  int c = lane << 1;
  float2 acc;
  {
    float e = as_n[(n << 2) + myh] + adst2;
    e = e > 0.f ? e : NEG * e;
    float al = __expf(e - mH) * inv;
    const float2 hv = *(const float2*)(h + (n << 7) + c);
    acc.x = al * hv.x; acc.y = al * hv.y;
  }
  for (int j0 = beg; j0 < end; j0 += 64) {
    int jn = end - j0; if (jn > 64) jn = 64;
    int sl = (j0 + lane < end) ? esrc[j0 + lane] : 0;
    for (int jj = 0; jj < jn; ++jj) {
      int sg = nodebase + __shfl(sl, jj);
      float e = as_n[(sg << 2) + myh] + adst2;
      e = e > 0.f ? e : NEG * e;
      float al = __expf(e - mH) * inv;
      const float2 hv = *(const float2*)(h + (sg << 7) + c);
      acc.x = fmaf(al, hv.x, acc.x);
      acc.y = fmaf(al, hv.y, acc.y);
    }
  }
  const float2 bi = *(const float2*)(bias + c);
  float2 o; o.x = acc.x + bi.x; o.y = acc.y + bi.y;
  *(float2*)(out + (n << 7) + c) = o;
}

// ---------------------------------------------------------------------- host
extern "C" void kernel_launch(void* const* d_in, const int* in_sizes, int n_in,
                              void* d_out, int out_size, void* d_ws, size_t ws_size,
                              hipStream_t stream) {
  const float* x    = (const float*)d_in[0];
  const void*  ei   = d_in[1];
  const float* W    = (const float*)d_in[2];
  const float* atts = (const float*)d_in[3];
  const float* attd = (const float*)d_in[4];
  const float* bias = (const float*)d_in[5];
  float* out = (float*)d_out;

  int N = in_sizes[0] / DIMD;   // 16384
  int E = in_sizes[1] / 2;      // 131072

  char* p = (char*)d_ws;
  float* h      = (float*)p; p += (size_t)N * DIMD * 4;
  float* as_n   = (float*)p; p += (size_t)N * NHEAD * 4;
  float* ad_n   = (float*)p; p += (size_t)N * NHEAD * 4;
  int*   counts = (int*)p;   p += (size_t)TPG * 4;
  int*   offs   = (int*)p;   p += (size_t)(TPG + 1) * 4;
  int*   cursor = (int*)p;   p += (size_t)TPG * 4;
  int*   esrc   = (int*)p;   p += (size_t)E * 4;
  int*   flag   = (int*)p;   p += 4;

  k_detect<<<1, 64, 0, stream>>>((const unsigned int*)ei, flag);
  k_zero<<<(TPG + 255) / 256, 256, 0, stream>>>(counts, TPG);
  k_gemm<<<N / 16, 256, 0, stream>>>(x, W, atts, attd, h, as_n, ad_n);
  k_hist<<<(E + 255) / 256, 256, 0, stream>>>(ei, flag, counts, E);
  k_scan<<<1, 1024, 0, stream>>>(counts, offs, cursor);
  k_scatter<<<(E + 255) / 256, 256, 0, stream>>>(ei, flag, cursor, esrc, E);
  k_aggr<<<N / 4, 256, 0, stream>>>(offs, esrc, h, as_n, ad_n, bias, out);
}

// Round 2
// 153.165 us; speedup vs baseline: 1.1469x; 1.1469x over previous
//
#include <hip/hip_runtime.h>

#define TPG   4096    // nodes per graph (T)
#define NHEAD 4
#define DIMD  128
#define NEG   0.2f

// ---------------------------------------------------------------- edge loads
__device__ __forceinline__ int load_edge(const void* ei, int is64, long idx) {
  if (is64) return (int)((const long long*)ei)[idx];
  return ((const int*)ei)[idx];
}

// Per-block int64/int32 layout vote: 256 threads sample odd dwords 1..511.
// int64 => high dwords all 0. int32 => those dwords are node ids ~U[0,4096),
// 256 simultaneous zeros is impossible in practice.
__device__ __forceinline__ int detect64_block(const unsigned* __restrict__ ei) {
  __shared__ int s64;
  int t = threadIdx.x;
  if (t == 0) s64 = 1;
  __syncthreads();
  if (t < 256) {
    unsigned v = ei[2 * t + 1];
    if (v != 0u) s64 = 0;     // benign race: all writers write 0
  }
  __syncthreads();
  return s64;
}

// ------------------------------------------------- GEMM h = x*W^T + att dots
// block = 256 threads, 16 nodes/block. thread(n_sub = t&15, cgrp = t>>4)
// computes 8 channels c = cgrp*8 .. +7. Wave w owns head w exactly.
// Also zeroes the 4096 hist counters (blocks 0..15) - runs before k_hist.
__global__ __launch_bounds__(256) void k_gemm(
    const float* __restrict__ x, const float* __restrict__ W,
    const float* __restrict__ atts, const float* __restrict__ attd,
    float* __restrict__ h, float* __restrict__ as_n, float* __restrict__ ad_n,
    int* __restrict__ counts) {
  __shared__ float4 xs4[16][33];   // +1 float4 pad
  int t = threadIdx.x;
  if (blockIdx.x < 16) counts[(blockIdx.x << 8) + t] = 0;
  int base = blockIdx.x * 16;
  const float4* x4 = (const float4*)x;
  for (int i = t; i < 512; i += 256) {
    xs4[i >> 5][i & 31] = x4[base * 32 + i];
  }
  __syncthreads();

  int n_sub = t & 15, cgrp = t >> 4;
  int c0 = cgrp * 8;
  const float4* W4 = (const float4*)W;
  float acc[8];
#pragma unroll
  for (int k = 0; k < 8; ++k) acc[k] = 0.f;

  for (int db = 0; db < 32; db += 8) {     // 32 d per chunk
    float4 xa[8];
#pragma unroll
    for (int i = 0; i < 8; ++i) xa[i] = xs4[n_sub][db + i];
#pragma unroll
    for (int k = 0; k < 8; ++k) {
      const float4* wr = W4 + (c0 + k) * 32 + db;
      float a = acc[k];
#pragma unroll
      for (int i = 0; i < 8; ++i) {
        float4 w = wr[i];
        a = fmaf(xa[i].x, w.x, a);
        a = fmaf(xa[i].y, w.y, a);
        a = fmaf(xa[i].z, w.z, a);
        a = fmaf(xa[i].w, w.w, a);
      }
      acc[k] = a;
    }
  }

  int n = base + n_sub;
  float4* hp = (float4*)(h + (n << 7) + c0);
  hp[0] = make_float4(acc[0], acc[1], acc[2], acc[3]);
  hp[1] = make_float4(acc[4], acc[5], acc[6], acc[7]);

  // attention dots: head = wave id; reduce over 4 cgrps via xor 16,32
  float ps = 0.f, pd = 0.f;
#pragma unroll
  for (int k = 0; k < 8; ++k) {
    ps = fmaf(acc[k], atts[c0 + k], ps);
    pd = fmaf(acc[k], attd[c0 + k], pd);
  }
  ps += __shfl_xor(ps, 16); ps += __shfl_xor(ps, 32);
  pd += __shfl_xor(pd, 16); pd += __shfl_xor(pd, 32);
  if ((t & 48) == 0) {                 // lanes 0..15 of each wave
    as_n[(n << 2) + (t >> 6)] = ps;
    ad_n[(n << 2) + (t >> 6)] = pd;
  }
}

// ------------------------------------------------------------------ CSR build
__global__ __launch_bounds__(256) void k_hist(const void* __restrict__ ei,
                                              int* __restrict__ counts, int E) {
  int is64 = detect64_block((const unsigned*)ei);
  int e = blockIdx.x * blockDim.x + threadIdx.x;
  if (e >= E) return;
  int dst = load_edge(ei, is64, (long)E + e);
  atomicAdd(&counts[dst], 1);
}

__global__ __launch_bounds__(1024) void k_scan(const int* __restrict__ counts,
                                               int* __restrict__ offs,
                                               int* __restrict__ cursor) {
  __shared__ int wsum[16];
  __shared__ int woff[17];
  int t = threadIdx.x;
  int b = t * 4;
  int v0 = counts[b], v1 = counts[b + 1], v2 = counts[b + 2], v3 = counts[b + 3];
  int s0 = v0 + v1 + v2 + v3;
  int lane = t & 63, w = t >> 6;
  int sc = s0;
#pragma unroll
  for (int off = 1; off < 64; off <<= 1) {
    int o = __shfl_up(sc, off);
    if (lane >= off) sc += o;
  }
  if (lane == 63) wsum[w] = sc;
  __syncthreads();
  if (t == 0) {
    int a = 0;
#pragma unroll
    for (int i = 0; i < 16; ++i) { woff[i] = a; a += wsum[i]; }
    woff[16] = a;
  }
  __syncthreads();
  int a = woff[w] + sc - s0;   // exclusive prefix of this thread's chunk
  offs[b] = a;     cursor[b] = a;     a += v0;
  offs[b + 1] = a; cursor[b + 1] = a; a += v1;
  offs[b + 2] = a; cursor[b + 2] = a; a += v2;
  offs[b + 3] = a; cursor[b + 3] = a;
  if (t == 1023) offs[4096] = woff[16];
}

__global__ __launch_bounds__(256) void k_scatter(const void* __restrict__ ei,
                                                 int* __restrict__ cursor,
                                                 int* __restrict__ esrc, int E) {
  int is64 = detect64_block((const unsigned*)ei);
  int e = blockIdx.x * blockDim.x + threadIdx.x;
  if (e >= E) return;
  int src = load_edge(ei, is64, e);
  int dst = load_edge(ei, is64, (long)E + e);
  int pos = atomicAdd(&cursor[dst], 1);
  esrc[pos] = src;
}

// --------------------------- single-pass flash softmax + aggregation per node
// one wave per node; lane owns channels 2l,2l+1, head = lane>>4.
// Edges consumed in batches of 8: scalar (SGPR) esrc loads, 8 h-row gathers
// in flight, one branch-free rescale per batch. No shfl, no atomics.
__global__ __launch_bounds__(256) void k_aggr(
    const int* __restrict__ offs, const int* __restrict__ esrc,
    const float* __restrict__ h, const float* __restrict__ as_n,
    const float* __restrict__ ad_n, const float* __restrict__ bias,
    float* __restrict__ out) {
  int lane = threadIdx.x & 63;
  int n = __builtin_amdgcn_readfirstlane((blockIdx.x << 2) + (threadIdx.x >> 6));
  int tloc = n & (TPG - 1);
  int nodebase = n - tloc;
  int beg = __builtin_amdgcn_readfirstlane(offs[tloc]);
  int end = __builtin_amdgcn_readfirstlane(offs[tloc + 1]);

  int myh = lane >> 4;
  int c = lane << 1;
  float adst = ad_n[(n << 2) + myh];

  // self-loop initializes the online state
  float m, s;
  float2 acc;
  {
    float e = as_n[(n << 2) + myh] + adst;
    e = e > 0.f ? e : NEG * e;
    m = e; s = 1.f;
    acc = *(const float2*)(h + ((size_t)n << 7) + c);
  }

  for (int j0 = beg; j0 < end; j0 += 8) {
    int sgk[8];
#pragma unroll
    for (int k = 0; k < 8; ++k) {
      int j = j0 + k;
      sgk[k] = (j < end) ? (nodebase + esrc[j]) : n;   // scalar s_load chain
    }
    float ek[8];
#pragma unroll
    for (int k = 0; k < 8; ++k) {
      float e = as_n[((size_t)sgk[k] << 2) + myh] + adst;
      e = e > 0.f ? e : NEG * e;
      ek[k] = (j0 + k < end) ? e : -1e30f;             // tail contributes 0
    }
    float2 hv[8];
#pragma unroll
    for (int k = 0; k < 8; ++k)
      hv[k] = *(const float2*)(h + ((size_t)sgk[k] << 7) + c);

    float bm = ek[0];
#pragma unroll
    for (int k = 1; k < 8; ++k) bm = fmaxf(bm, ek[k]);
    float mn = fmaxf(m, bm);
    float r = __expf(m - mn);
    float ps = 0.f, px = 0.f, py = 0.f;
#pragma unroll
    for (int k = 0; k < 8; ++k) {
      float al = __expf(ek[k] - mn);
      ps += al;
      px = fmaf(al, hv[k].x, px);
      py = fmaf(al, hv[k].y, py);
    }
    acc.x = fmaf(acc.x, r, px);
    acc.y = fmaf(acc.y, r, py);
    s = fmaf(s, r, ps);
    m = mn;
  }

  float invs = 1.f / (s + 1e-16f);
  const float2 bi = *(const float2*)(bias + c);
  float2 o;
  o.x = fmaf(acc.x, invs, bi.x);
  o.y = fmaf(acc.y, invs, bi.y);
  *(float2*)(out + ((size_t)n << 7) + c) = o;
}

// ---------------------------------------------------------------------- host
extern "C" void kernel_launch(void* const* d_in, const int* in_sizes, int n_in,
                              void* d_out, int out_size, void* d_ws, size_t ws_size,
                              hipStream_t stream) {
  const float* x    = (const float*)d_in[0];
  const void*  ei   = d_in[1];
  const float* W    = (const float*)d_in[2];
  const float* atts = (const float*)d_in[3];
  const float* attd = (const float*)d_in[4];
  const float* bias = (const float*)d_in[5];
  float* out = (float*)d_out;

  int N = in_sizes[0] / DIMD;   // 16384
  int E = in_sizes[1] / 2;      // 131072

  char* p = (char*)d_ws;
  float* h      = (float*)p; p += (size_t)N * DIMD * 4;
  float* as_n   = (float*)p; p += (size_t)N * NHEAD * 4;
  float* ad_n   = (float*)p; p += (size_t)N * NHEAD * 4;
  int*   counts = (int*)p;   p += (size_t)TPG * 4;
  int*   offs   = (int*)p;   p += (size_t)(TPG + 1) * 4;
  int*   cursor = (int*)p;   p += (size_t)TPG * 4;
  int*   esrc   = (int*)p;   p += (size_t)E * 4;

  k_gemm<<<N / 16, 256, 0, stream>>>(x, W, atts, attd, h, as_n, ad_n, counts);
  k_hist<<<(E + 255) / 256, 256, 0, stream>>>(ei, counts, E);
  k_scan<<<1, 1024, 0, stream>>>(counts, offs, cursor);
  k_scatter<<<(E + 255) / 256, 256, 0, stream>>>(ei, cursor, esrc, E);
  k_aggr<<<N / 4, 256, 0, stream>>>(offs, esrc, h, as_n, ad_n, bias, out);
}